// Round 1
// baseline (2648.059 us; speedup 1.0000x reference)
//
#include <hip/hip_runtime.h>
#include <math.h>

#define NATOMS 100000
#define M 12
#define A 64
#define F 41
#define C1 128    // 2A
#define TOTF 169  // 2A+F
#define NMROWS (NATOMS * M)

// ---- workspace layout (float offsets) ----
#define OFF_WEFF   0                         // [3][41][128] = 15744
#define OFF_BEFF   15744                     // [3][128]     = 384
#define OFF_SUM1   16128                     // [384]
#define OFF_SQ1    16512                     // [384]
#define OFF_SUM2   16896                     // [192]
#define OFF_SQ2    17088                     // [192]  (SUM1..SQ2 = 1152 contiguous, memset to 0)
#define OFF_SCA    17280                     // scaleA [384]
#define OFF_SHA    17664                     // shiftA [384]
#define OFF_SCB    18048                     // scaleB [192]
#define OFF_SHB    18240                     // shiftB [192]
#define OFF_P      32768                     // P_all [N][768]
#define OFF_SUMMED (OFF_P + (size_t)NATOMS*768)  // [3][N][64]
#define OFF_Q      OFF_P                     // q [N][192] overlays dead P

__device__ __forceinline__ float sigmoidf_(float x) {
    return 1.0f / (1.0f + __expf(-x));
}
__device__ __forceinline__ float softplusf_(float x) {
    return fmaxf(x, 0.0f) + __logf(1.0f + __expf(-fabsf(x)));
}

// K0: W_eff[s] = (s==0 ? W_nf0 : W_scale[s-1] @ W_nf_s), b_eff[s] = b_full[s] + b_scale[s-1] @ W_nf_s
__global__ void k_weff(const float* __restrict__ Wf, const float* __restrict__ bf,
                       const float* __restrict__ Wsc, const float* __restrict__ bsc,
                       float* __restrict__ ws) {
    int j = threadIdx.x;  // 128
    float* We = ws + OFF_WEFF;
    float* be = ws + OFF_BEFF;
    for (int s = 0; s < 3; ++s) {
        float bb = bf[s * C1 + j];
        if (s > 0) {
            for (int q = 0; q < F; ++q)
                bb += bsc[(s - 1) * F + q] * Wf[(s * TOTF + 128 + q) * C1 + j];
        }
        be[s * C1 + j] = bb;
        for (int k = 0; k < F; ++k) {
            float v;
            if (s == 0) {
                v = Wf[(0 * TOTF + 128 + k) * C1 + j];
            } else {
                v = 0.0f;
                for (int q = 0; q < F; ++q)
                    v += Wsc[((s - 1) * F + k) * F + q] * Wf[(s * TOTF + 128 + q) * C1 + j];
            }
            We[(s * F + k) * C1 + j] = v;
        }
    }
}

// K1: P[a][s*256+u] = atom_fea[a] . W_full[s][(u<128 ? rows 0..63 : rows 64..127)][u&127]
__global__ __launch_bounds__(256) void k_pall(const float* __restrict__ atom,
                                              const float* __restrict__ Wf,
                                              float* __restrict__ ws) {
    int u = threadIdx.x;
    int s = blockIdx.x;  // 0..2
    float wcol[A];
    int colw = u & 127;
#pragma unroll
    for (int k = 0; k < A; ++k) {
        int row = (u < 128) ? k : (A + k);
        wcol[k] = Wf[(s * TOTF + row) * C1 + colw];
    }
    float* P = ws + OFF_P;
    for (int a = blockIdx.y; a < NATOMS; a += gridDim.y) {
        const float* ar = atom + (size_t)a * A;  // wave-uniform -> s_load
        float acc = 0.0f;
#pragma unroll
        for (int k = 0; k < A; ++k) acc = fmaf(ar[k], wcol[k], acc);
        P[(size_t)a * 768 + s * 256 + u] = acc;
    }
}

// K2 (PASS=0): z stats.  K4 (PASS=1): apply BN1, activation, sum over m, write summed, BN2 stats.
// block = 192 threads = 3 waves; wave = scale s; lane j owns z columns j (filt) and j+64 (core).
template <int PASS>
__global__ __launch_bounds__(192) void k_conv(const float* __restrict__ nbr,
                                              const int* __restrict__ idx,
                                              float* __restrict__ ws) {
    int tid = threadIdx.x;
    int s = tid >> 6;
    int j = tid & 63;
    const float* We = ws + OFF_WEFF;
    const float* be = ws + OFF_BEFF;
    const float* P = ws + OFF_P;
    float w1[F], w2[F];
#pragma unroll
    for (int k = 0; k < F; ++k) {
        w1[k] = We[(s * F + k) * C1 + j];
        w2[k] = We[(s * F + k) * C1 + 64 + j];
    }
    float b1 = be[s * C1 + j], b2 = be[s * C1 + 64 + j];
    float sc1 = 0.f, sh1 = 0.f, sc2 = 0.f, sh2 = 0.f;
    if (PASS == 1) {
        sc1 = ws[OFF_SCA + s * C1 + j];
        sh1 = ws[OFF_SHA + s * C1 + j];
        sc2 = ws[OFF_SCA + s * C1 + 64 + j];
        sh2 = ws[OFF_SHA + s * C1 + 64 + j];
    }
    float accA = 0.f, accB = 0.f, accC = 0.f, accD = 0.f;
    float* summed = ws + OFF_SUMMED;
    for (int a = blockIdx.x; a < NATOMS; a += gridDim.x) {
        float ps1 = P[(size_t)a * 768 + s * 256 + j];
        float ps2 = P[(size_t)a * 768 + s * 256 + 64 + j];
        float hsum = 0.0f;
        for (int m = 0; m < M; ++m) {
            int pair = a * M + m;
            int row = idx[pair];                      // wave-uniform scalar load
            const float* x = nbr + (size_t)pair * F;  // wave-uniform -> s_load
            float z1 = b1 + ps1 + P[(size_t)row * 768 + s * 256 + 128 + j];
            float z2 = b2 + ps2 + P[(size_t)row * 768 + s * 256 + 192 + j];
#pragma unroll
            for (int k = 0; k < F; ++k) {
                float xv = x[k];
                z1 = fmaf(xv, w1[k], z1);
                z2 = fmaf(xv, w2[k], z2);
            }
            if (PASS == 0) {
                accA += z1; accB += z1 * z1;
                accC += z2; accD += z2 * z2;
            } else {
                float f = fmaf(z1, sc1, sh1);
                float c = fmaf(z2, sc2, sh2);
                hsum += sigmoidf_(f) * softplusf_(c);
            }
        }
        if (PASS == 1) {
            summed[((size_t)s * NATOMS + a) * 64 + j] = hsum;
            accA += hsum;
            accB += hsum * hsum;
        }
    }
    if (PASS == 0) {
        atomicAdd(&ws[OFF_SUM1 + s * C1 + j], accA);
        atomicAdd(&ws[OFF_SQ1 + s * C1 + j], accB);
        atomicAdd(&ws[OFF_SUM1 + s * C1 + 64 + j], accC);
        atomicAdd(&ws[OFF_SQ1 + s * C1 + 64 + j], accD);
    } else {
        atomicAdd(&ws[OFF_SUM2 + s * 64 + j], accA);
        atomicAdd(&ws[OFF_SQ2 + s * 64 + j], accB);
    }
}

// K3: BN1 params from stats
__global__ void k_bn1(const float* __restrict__ g1, const float* __restrict__ bt1,
                      float* __restrict__ ws) {
    int c = threadIdx.x;  // 384
    float inv = 1.0f / (float)NMROWS;
    float mu = ws[OFF_SUM1 + c] * inv;
    float var = ws[OFF_SQ1 + c] * inv - mu * mu;
    float rs = rsqrtf(var + 1e-5f);
    float g = g1[c];
    ws[OFF_SCA + c] = g * rs;
    ws[OFF_SHA + c] = bt1[c] - mu * rs * g;
}

// K5: BN2 params from stats
__global__ void k_bn2(const float* __restrict__ g2, const float* __restrict__ bt2,
                      float* __restrict__ ws) {
    int c = threadIdx.x;  // 192
    float inv = 1.0f / (float)NATOMS;
    float mu = ws[OFF_SUM2 + c] * inv;
    float var = ws[OFF_SQ2 + c] * inv - mu * mu;
    float rs = rsqrtf(var + 1e-5f);
    float g = g2[c];
    ws[OFF_SCB + c] = g * rs;
    ws[OFF_SHB + c] = bt2[c] - mu * rs * g;
}

// K5b: q[a][s*64+j] = softplus(atom_fea[a][j] + bn2(summed))   (q overlays P)
__global__ __launch_bounds__(256) void k_q(const float* __restrict__ atom,
                                           float* __restrict__ ws) {
    size_t e = (size_t)blockIdx.x * 256 + threadIdx.x;
    if (e >= (size_t)NATOMS * 192) return;
    int a = (int)(e / 192);
    int c = (int)(e % 192);
    int s = c >> 6;
    int j = c & 63;
    float v = ws[OFF_SUMMED + ((size_t)s * NATOMS + a) * 64 + j];
    v = fmaf(v, ws[OFF_SCB + c], ws[OFF_SHB + c]);
    v += atom[(size_t)a * A + j];
    ws[OFF_Q + (size_t)a * 192 + c] = softplusf_(v);
}

// K6: out = relu(q @ W_fuse + b_fuse).  1 wave/block; lane owns output col o,
// W_fuse column in 192 VGPRs, q row via wave-uniform scalar loads.
__global__ __launch_bounds__(64, 2) void k_fuse(const float* __restrict__ Wfu,
                                                const float* __restrict__ bfu,
                                                const float* __restrict__ ws,
                                                float* __restrict__ out) {
    int o = threadIdx.x;
    float wcol[192];
#pragma unroll
    for (int k = 0; k < 192; ++k) wcol[k] = Wfu[k * 64 + o];
    float bb = bfu[o];
    const float* q = ws + OFF_Q;
    for (int a = blockIdx.x; a < NATOMS; a += gridDim.x) {
        const float* qr = q + (size_t)a * 192;  // wave-uniform -> s_load
        float acc = bb;
#pragma unroll
        for (int k = 0; k < 192; ++k) acc = fmaf(qr[k], wcol[k], acc);
        out[(size_t)a * 64 + o] = fmaxf(acc, 0.0f);
    }
}

extern "C" void kernel_launch(void* const* d_in, const int* in_sizes, int n_in,
                              void* d_out, int out_size, void* d_ws, size_t ws_size,
                              hipStream_t stream) {
    const float* atom = (const float*)d_in[0];   // [N,64]
    const float* nbr  = (const float*)d_in[1];   // [N,12,41]
    const int*   idx  = (const int*)d_in[2];     // [N,12]
    const float* Wf   = (const float*)d_in[3];   // [3,169,128]
    const float* bf   = (const float*)d_in[4];   // [3,128]
    const float* g1   = (const float*)d_in[5];   // [3,128]
    const float* bt1  = (const float*)d_in[6];   // [3,128]
    const float* g2   = (const float*)d_in[7];   // [3,64]
    const float* bt2  = (const float*)d_in[8];   // [3,64]
    const float* Wsc  = (const float*)d_in[9];   // [2,41,41]
    const float* bsc  = (const float*)d_in[10];  // [2,41]
    const float* Wfu  = (const float*)d_in[11];  // [192,64]
    const float* bfu  = (const float*)d_in[12];  // [64]
    float* out = (float*)d_out;
    float* ws = (float*)d_ws;

    // zero the stats accumulators (ws is poisoned 0xAA before every call)
    hipMemsetAsync((char*)d_ws + OFF_SUM1 * sizeof(float), 0, 1152 * sizeof(float), stream);

    k_weff<<<1, 128, 0, stream>>>(Wf, bf, Wsc, bsc, ws);
    k_pall<<<dim3(3, 512), 256, 0, stream>>>(atom, Wf, ws);
    k_conv<0><<<1280, 192, 0, stream>>>(nbr, idx, ws);
    k_bn1<<<1, 384, 0, stream>>>(g1, bt1, ws);
    k_conv<1><<<1280, 192, 0, stream>>>(nbr, idx, ws);
    k_bn2<<<1, 192, 0, stream>>>(g2, bt2, ws);
    k_q<<<(NATOMS * 192 + 255) / 256, 256, 0, stream>>>(atom, ws);
    k_fuse<<<2048, 64, 0, stream>>>(Wfu, bfu, ws, out);
}